// Round 2
// baseline (117.743 us; speedup 1.0000x reference)
//
#include <hip/hip_runtime.h>

#define BB 4
#define RR 64
#define FF 1024
#define DD 128

// ws layout (floats): fpT[B][D][F] | rproj[B*R][D] | wd[D]
static constexpr int RPROJ_OFF = BB * DD * FF;            // 524288
static constexpr int WD_OFF    = RPROJ_OFF + BB * RR * DD; // 557056

__global__ __launch_bounds__(128) void proj_kernel(
    const float* __restrict__ robot, const float* __restrict__ frontier,
    const float* __restrict__ W1, float* __restrict__ ws) {
  float* fpT   = ws;
  float* rproj = ws + RPROJ_OFF;
  float* wd    = ws + WD_OFF;
  const int blk = blockIdx.x;
  const int d   = threadIdx.x;
  __shared__ float rows[8][DD];

  if (blk < (BB * FF) / 8) {
    // f_proj for 8 frontier rows, written TRANSPOSED: fpT[b][d][f]
    const int base = blk * 8;  // flat (b,f) row
    #pragma unroll
    for (int i = 0; i < 8; ++i) rows[i][d] = frontier[(base + i) * DD + d];
    __syncthreads();
    float acc[8] = {0.f,0.f,0.f,0.f,0.f,0.f,0.f,0.f};
    #pragma unroll 4
    for (int k = 0; k < DD; ++k) {
      const float w = W1[(DD + k) * DD + d];   // W1f, coalesced over d
      #pragma unroll
      for (int i = 0; i < 8; ++i) acc[i] = fmaf(rows[i][k], w, acc[i]);
    }
    const int b  = base / FF;
    const int f0 = base % FF;
    float* dst = fpT + (size_t)(b * DD + d) * FF + f0;
    *reinterpret_cast<float4*>(dst)     = make_float4(acc[0], acc[1], acc[2], acc[3]);
    *reinterpret_cast<float4*>(dst + 4) = make_float4(acc[4], acc[5], acc[6], acc[7]);
  } else if (blk < (BB * FF) / 8 + (BB * RR) / 8) {
    // r_proj for 8 robot rows, natural layout
    const int base = (blk - (BB * FF) / 8) * 8;  // flat (b,r) row
    #pragma unroll
    for (int i = 0; i < 8; ++i) rows[i][d] = robot[(base + i) * DD + d];
    __syncthreads();
    float acc[8] = {0.f,0.f,0.f,0.f,0.f,0.f,0.f,0.f};
    #pragma unroll 4
    for (int k = 0; k < DD; ++k) {
      const float w = W1[k * DD + d];          // W1r
      #pragma unroll
      for (int i = 0; i < 8; ++i) acc[i] = fmaf(rows[i][k], w, acc[i]);
    }
    #pragma unroll
    for (int i = 0; i < 8; ++i) rproj[(base + i) * DD + d] = acc[i];
  } else {
    // wd[d] = sum_k W1d[k][d]
    float acc = 0.f;
    #pragma unroll 4
    for (int k = 0; k < DD; ++k) acc += W1[(2 * DD + k) * DD + d];
    wd[d] = acc;
  }
}

__global__ __launch_bounds__(512) void fused_kernel(
    const float* __restrict__ robot, const float* __restrict__ frontier,
    const float* __restrict__ geo,
    const float* __restrict__ b1, const float* __restrict__ W2,
    const float* __restrict__ b2, const float* __restrict__ Wn,
    const float* __restrict__ bn,
    const float* __restrict__ ws, float* __restrict__ out) {
  const int br = blockIdx.x;          // b*R + r
  const int b  = br >> 6;
  const int t  = threadIdx.x;

  const float* fpT   = ws;
  const float* rproj = ws + RPROJ_OFF;
  const float* wd    = ws + WD_OFF;

  __shared__ float rpb[DD], wds[DD], w2s[DD];
  __shared__ float wlds[FF];
  __shared__ float part4[4][DD];
  __shared__ float combs[2 * DD];
  __shared__ float red[16];

  if (t < DD) {
    rpb[t] = rproj[br * DD + t] + b1[t];   // hoist r_proj + b1
    wds[t] = wd[t];
    w2s[t] = W2[t];
  }
  __syncthreads();

  // ---- scores: each thread owns f = t and f = t+512 ----
  const float g0 = geo[(size_t)br * FF + t];
  const float g1 = geo[(size_t)br * FF + t + 512];
  const float* fb = fpT + (size_t)b * DD * FF;
  float acc0 = 0.f, acc1 = 0.f;
  #pragma unroll 4
  for (int d = 0; d < DD; ++d) {
    const float fp0 = fb[d * FF + t];        // coalesced (transposed layout)
    const float fp1 = fb[d * FF + t + 512];
    const float c = rpb[d], wv = wds[d], w2v = w2s[d];
    float h0 = fmaf(g0, wv, c) + fp0;
    float h1 = fmaf(g1, wv, c) + fp1;
    h0 = fmaxf(h0, 0.f);
    h1 = fmaxf(h1, 0.f);
    acc0 = fmaf(h0, w2v, acc0);
    acc1 = fmaf(h1, w2v, acc1);
  }
  const float b2v = b2[0];
  const float s0 = fmaxf(acc0 + b2v, 0.f);
  const float s1 = fmaxf(acc1 + b2v, 0.f);

  // ---- softmax over 1024 values ----
  float m = fmaxf(s0, s1);
  #pragma unroll
  for (int off = 32; off >= 1; off >>= 1) m = fmaxf(m, __shfl_xor(m, off, 64));
  if ((t & 63) == 0) red[t >> 6] = m;
  __syncthreads();
  float bm = red[0];
  #pragma unroll
  for (int i = 1; i < 8; ++i) bm = fmaxf(bm, red[i]);
  const float e0 = __expf(s0 - bm);
  const float e1 = __expf(s1 - bm);
  float sum = e0 + e1;
  #pragma unroll
  for (int off = 32; off >= 1; off >>= 1) sum += __shfl_xor(sum, off, 64);
  if ((t & 63) == 0) red[8 + (t >> 6)] = sum;
  __syncthreads();
  float bs = 0.f;
  #pragma unroll
  for (int i = 0; i < 8; ++i) bs += red[8 + i];
  const float inv = 1.0f / bs;
  const float w0 = e0 * inv, w1 = e1 * inv;
  wlds[t]       = w0;
  wlds[t + 512] = w1;
  float* ew = out + BB * RR * DD;   // edge_weights output
  ew[(size_t)br * FF + t]       = w0;
  ew[(size_t)br * FF + t + 512] = w1;
  __syncthreads();

  // ---- messages: msg[d] = sum_f w[f]*frontier[b][f][d]; threads = (fq, d) ----
  {
    const int d = t & 127, fq = t >> 7;
    const float* fr = frontier + (size_t)b * FF * DD;
    float macc = 0.f;
    #pragma unroll 4
    for (int i = 0; i < 256; ++i) {
      const int f = fq * 256 + i;
      macc = fmaf(wlds[f], fr[f * DD + d], macc);  // coalesced over d
    }
    part4[fq][d] = macc;
  }
  __syncthreads();
  if (t < DD) {
    combs[DD + t] = part4[0][t] + part4[1][t] + part4[2][t] + part4[3][t];
  } else if (t < 2 * DD) {
    combs[t - DD] = robot[(size_t)br * DD + (t - DD)];
  }
  __syncthreads();

  // ---- new_robot[j] = relu(sum_k combs[k]*Wn[k][j] + bn[j]); threads = (kh, j) ----
  {
    const int j = t & 127, kh = t >> 7;
    float facc = 0.f;
    #pragma unroll 4
    for (int i = 0; i < 64; ++i) {
      const int k = kh * 64 + i;
      facc = fmaf(combs[k], Wn[k * DD + j], facc);  // coalesced over j
    }
    part4[kh][j] = facc;
  }
  __syncthreads();
  if (t < DD) {
    const float v = part4[0][t] + part4[1][t] + part4[2][t] + part4[3][t] + bn[t];
    out[(size_t)br * DD + t] = fmaxf(v, 0.f);
  }
}

extern "C" void kernel_launch(void* const* d_in, const int* in_sizes, int n_in,
                              void* d_out, int out_size, void* d_ws, size_t ws_size,
                              hipStream_t stream) {
  const float* robot    = (const float*)d_in[0];
  const float* frontier = (const float*)d_in[1];
  const float* geo      = (const float*)d_in[2];
  const float* W1       = (const float*)d_in[3];
  const float* b1       = (const float*)d_in[4];
  const float* W2       = (const float*)d_in[5];
  const float* b2       = (const float*)d_in[6];
  const float* Wn       = (const float*)d_in[7];
  const float* bn       = (const float*)d_in[8];
  float* out = (float*)d_out;
  float* ws  = (float*)d_ws;

  const int grid1 = (BB * FF) / 8 + (BB * RR) / 8 + 1;  // 545
  proj_kernel<<<grid1, 128, 0, stream>>>(robot, frontier, W1, ws);
  fused_kernel<<<BB * RR, 512, 0, stream>>>(robot, frontier, geo, b1, W2, b2,
                                            Wn, bn, ws, out);
}

// Round 3
// 102.043 us; speedup vs baseline: 1.1539x; 1.1539x over previous
//
#include <hip/hip_runtime.h>

#define BB 4
#define RR 64
#define FF 1024
#define DD 128
#define ROWS 32

// ws layout (floats): fpT[B][D][F] | rproj[B*R][D] | wd[D]
static constexpr int RPROJ_OFF = BB * DD * FF;             // 524288
static constexpr int WD_OFF    = RPROJ_OFF + BB * RR * DD; // 557056

__global__ __launch_bounds__(256) void proj_kernel(
    const float* __restrict__ robot, const float* __restrict__ frontier,
    const float* __restrict__ W1, float* __restrict__ ws) {
  float* fpT   = ws;
  float* rproj = ws + RPROJ_OFF;
  float* wd    = ws + WD_OFF;
  const int blk = blockIdx.x;
  const int t   = threadIdx.x;
  constexpr int NF = (BB * FF) / ROWS;  // 128
  constexpr int NR = (BB * RR) / ROWS;  // 8
  // phase 1: rows[f][k] = lds[f*128+k]; phase 2 (transpose): T[f][d] = lds[f*129+d]
  __shared__ float lds[ROWS * 129];

  if (blk < NF) {
    // ---- f_proj for 32 frontier rows, written transposed fpT[b][d][f] ----
    const int base = blk * ROWS;  // flat (b,f) row; 32 | 1024 so no b-crossing
    const float4* src = (const float4*)(frontier + (size_t)base * DD);
    #pragma unroll
    for (int i = 0; i < 4; ++i) ((float4*)lds)[t + 256 * i] = src[t + 256 * i];
    __syncthreads();
    const int d = t & 127, fh = t >> 7;  // fh selects 16-row half
    float acc[16];
    #pragma unroll
    for (int i = 0; i < 16; ++i) acc[i] = 0.f;
    #pragma unroll 4
    for (int k = 0; k < DD; ++k) {
      const float w = W1[(DD + k) * DD + d];  // W1f, coalesced over d
      #pragma unroll
      for (int i = 0; i < 16; ++i)
        acc[i] = fmaf(lds[(fh * 16 + i) * 128 + k], w, acc[i]);
    }
    __syncthreads();  // rows no longer needed; reuse lds as padded transpose tile
    #pragma unroll
    for (int i = 0; i < 16; ++i) lds[(fh * 16 + i) * 129 + d] = acc[i];
    __syncthreads();
    const int b = base / FF, f0 = base % FF;
    float* dst = fpT + (size_t)b * DD * FF + f0;
    #pragma unroll
    for (int j = 0; j < 8; ++j) {
      const int flat = t + j * 256;        // 4096 elems: (d,f) f-fastest
      const int dd = flat >> 5, f = flat & 31;
      dst[dd * FF + f] = lds[f * 129 + dd];  // pad-129: conflict-free read
    }
  } else if (blk < NF + NR) {
    // ---- r_proj for 32 robot rows, natural layout ----
    const int base = (blk - NF) * ROWS;
    const float4* src = (const float4*)(robot + (size_t)base * DD);
    #pragma unroll
    for (int i = 0; i < 4; ++i) ((float4*)lds)[t + 256 * i] = src[t + 256 * i];
    __syncthreads();
    const int d = t & 127, fh = t >> 7;
    float acc[16];
    #pragma unroll
    for (int i = 0; i < 16; ++i) acc[i] = 0.f;
    #pragma unroll 4
    for (int k = 0; k < DD; ++k) {
      const float w = W1[k * DD + d];  // W1r
      #pragma unroll
      for (int i = 0; i < 16; ++i)
        acc[i] = fmaf(lds[(fh * 16 + i) * 128 + k], w, acc[i]);
    }
    #pragma unroll
    for (int i = 0; i < 16; ++i)
      rproj[(size_t)(base + fh * 16 + i) * DD + d] = acc[i];  // coalesced over d
  } else if (t < DD) {
    // ---- wd[d] = colsum of W1d ----
    float acc = 0.f;
    #pragma unroll 4
    for (int k = 0; k < DD; ++k) acc += W1[(2 * DD + k) * DD + t];
    wd[t] = acc;
  }
}

__global__ __launch_bounds__(1024) void fused_kernel(
    const float* __restrict__ robot, const float* __restrict__ frontier,
    const float* __restrict__ geo,
    const float* __restrict__ b1, const float* __restrict__ W2,
    const float* __restrict__ b2, const float* __restrict__ Wn,
    const float* __restrict__ bn,
    const float* __restrict__ ws, float* __restrict__ out) {
  const int br = blockIdx.x;  // b*R + r
  const int b  = br >> 6;
  const int t  = threadIdx.x;

  const float* fpT   = ws;
  const float* rproj = ws + RPROJ_OFF;
  const float* wd    = ws + WD_OFF;

  __shared__ float rpb[DD], wds[DD], w2s[DD];
  __shared__ float wlds[FF];
  __shared__ float part[32][DD];   // message partials [f-group][d]
  __shared__ float red2[8][DD];    // 2nd-stage partials (reused for final matvec)
  __shared__ float combs[2 * DD];
  __shared__ float red[32];

  if (t < DD) {
    rpb[t] = rproj[br * DD + t] + b1[t];
    wds[t] = wd[t];
    w2s[t] = W2[t];
  }
  __syncthreads();

  // ---- scores: 1 f per thread ----
  const float g = geo[(size_t)br * FF + t];
  const float* fb = fpT + (size_t)b * DD * FF;
  float acc = 0.f;
  #pragma unroll 8
  for (int d = 0; d < DD; ++d) {
    const float h = fmaf(g, wds[d], rpb[d]) + fb[d * FF + t];  // coalesced 4KB/iter
    acc = fmaf(fmaxf(h, 0.f), w2s[d], acc);
  }
  const float s = fmaxf(acc + b2[0], 0.f);

  // ---- softmax over 1024 values, 16 waves ----
  float m = s;
  #pragma unroll
  for (int off = 32; off >= 1; off >>= 1) m = fmaxf(m, __shfl_xor(m, off, 64));
  if ((t & 63) == 0) red[t >> 6] = m;
  __syncthreads();
  float bm = red[0];
  #pragma unroll
  for (int i = 1; i < 16; ++i) bm = fmaxf(bm, red[i]);
  const float e = __expf(s - bm);
  float sum = e;
  #pragma unroll
  for (int off = 32; off >= 1; off >>= 1) sum += __shfl_xor(sum, off, 64);
  if ((t & 63) == 0) red[16 + (t >> 6)] = sum;
  __syncthreads();
  float bs = 0.f;
  #pragma unroll
  for (int i = 0; i < 16; ++i) bs += red[16 + i];
  const float w = e * (1.0f / bs);
  wlds[t] = w;
  float* ew = out + BB * RR * DD;  // edge_weights output
  ew[(size_t)br * FF + t] = w;
  __syncthreads();

  // ---- messages: msg[d] = sum_f w[f]*frontier[b][f][d]; float4 over d ----
  {
    const int c = t & 31, fg = t >> 5;  // 32 f-groups × 32 float4-columns
    const float4* fr4 = (const float4*)(frontier + (size_t)b * FF * DD);
    float ax = 0.f, ay = 0.f, az = 0.f, aw = 0.f;
    #pragma unroll 4
    for (int i = 0; i < 32; ++i) {
      const int f = fg * 32 + i;
      const float wf = wlds[f];           // broadcast
      const float4 v = fr4[f * 32 + c];   // 512B contiguous per 32 lanes
      ax = fmaf(wf, v.x, ax);
      ay = fmaf(wf, v.y, ay);
      az = fmaf(wf, v.z, az);
      aw = fmaf(wf, v.w, aw);
    }
    part[fg][4 * c]     = ax;
    part[fg][4 * c + 1] = ay;
    part[fg][4 * c + 2] = az;
    part[fg][4 * c + 3] = aw;
  }
  __syncthreads();
  {
    const int d = t & 127, gg = t >> 7;  // 8 groups of 4
    red2[gg][d] = part[gg * 4][d] + part[gg * 4 + 1][d] +
                  part[gg * 4 + 2][d] + part[gg * 4 + 3][d];
  }
  __syncthreads();
  if (t < DD) {
    float msg = 0.f;
    #pragma unroll
    for (int i = 0; i < 8; ++i) msg += red2[i][t];
    combs[DD + t] = msg;
  } else if (t < 2 * DD) {
    combs[t - DD] = robot[(size_t)br * DD + (t - DD)];
  }
  __syncthreads();

  // ---- new_robot[j] = relu(sum_k combs[k]*Wn[k][j] + bn[j]) ----
  {
    const int j = t & 127, kh = t >> 7;  // 8 k-groups of 32
    float fa = 0.f;
    #pragma unroll 8
    for (int i = 0; i < 32; ++i) {
      const int k = kh * 32 + i;
      fa = fmaf(combs[k], Wn[k * DD + j], fa);  // coalesced over j
    }
    red2[kh][j] = fa;  // safe: all prior red2 reads done at last barrier
  }
  __syncthreads();
  if (t < DD) {
    float v = bn[t];
    #pragma unroll
    for (int i = 0; i < 8; ++i) v += red2[i][t];
    out[(size_t)br * DD + t] = fmaxf(v, 0.f);
  }
}

extern "C" void kernel_launch(void* const* d_in, const int* in_sizes, int n_in,
                              void* d_out, int out_size, void* d_ws, size_t ws_size,
                              hipStream_t stream) {
  const float* robot    = (const float*)d_in[0];
  const float* frontier = (const float*)d_in[1];
  const float* geo      = (const float*)d_in[2];
  const float* W1       = (const float*)d_in[3];
  const float* b1       = (const float*)d_in[4];
  const float* W2       = (const float*)d_in[5];
  const float* b2       = (const float*)d_in[6];
  const float* Wn       = (const float*)d_in[7];
  const float* bn       = (const float*)d_in[8];
  float* out = (float*)d_out;
  float* ws  = (float*)d_ws;

  const int grid1 = (BB * FF) / ROWS + (BB * RR) / ROWS + 1;  // 137
  proj_kernel<<<grid1, 256, 0, stream>>>(robot, frontier, W1, ws);
  fused_kernel<<<BB * RR, 1024, 0, stream>>>(robot, frontier, geo, b1, W2, b2,
                                             Wn, bn, ws, out);
}

// Round 5
// 99.020 us; speedup vs baseline: 1.1891x; 1.0305x over previous
//
#include <hip/hip_runtime.h>

#define BB 4
#define RR 64
#define FF 1024
#define DD 128
#define ROWS 16

// ws layout (floats): fpT[B][D][F] | rproj[B*R][D] | wd[D]
static constexpr int RPROJ_OFF = BB * DD * FF;             // 524288
static constexpr int WD_OFF    = RPROJ_OFF + BB * RR * DD; // 557056

__global__ __launch_bounds__(256) void proj_kernel(
    const float* __restrict__ robot, const float* __restrict__ frontier,
    const float* __restrict__ W1, float* __restrict__ ws) {
  float* fpT   = ws;
  float* rproj = ws + RPROJ_OFF;
  float* wd    = ws + WD_OFF;
  const int blk = blockIdx.x;
  const int t   = threadIdx.x;
  constexpr int NF = (BB * FF) / ROWS;  // 256
  constexpr int NR = (BB * RR) / ROWS;  // 16
  // phase 1: rows[f][k] = lds[f*128+k]; phase 2 (transpose): T[f][d] = lds[f*129+d]
  __shared__ float lds[ROWS * 129];

  if (blk < NF) {
    // ---- f_proj for 16 frontier rows, written transposed fpT[b][d][f] ----
    const int base = blk * ROWS;  // flat (b,f) row; 16 | 1024 so no b-crossing
    const float4* src = (const float4*)(frontier + (size_t)base * DD);
    #pragma unroll
    for (int i = 0; i < 2; ++i) ((float4*)lds)[t + 256 * i] = src[t + 256 * i];
    __syncthreads();
    const int d = t & 127, fh = t >> 7;  // fh selects 8-row half
    float acc[8];
    #pragma unroll
    for (int i = 0; i < 8; ++i) acc[i] = 0.f;
    #pragma unroll 4
    for (int k = 0; k < DD; ++k) {
      const float w = W1[(DD + k) * DD + d];  // W1f, coalesced over d
      #pragma unroll
      for (int i = 0; i < 8; ++i)
        acc[i] = fmaf(lds[(fh * 8 + i) * 128 + k], w, acc[i]);
    }
    __syncthreads();  // rows no longer needed; reuse lds as padded transpose tile
    #pragma unroll
    for (int i = 0; i < 8; ++i) lds[(fh * 8 + i) * 129 + d] = acc[i];
    __syncthreads();
    // writeout: all 16x128 = 2048 elems as 512 float4 over f (2 per thread)
    const int b = base / FF, f0 = base % FF;
    float4* dst4 = (float4*)(fpT + (size_t)b * DD * FF + f0);
    #pragma unroll
    for (int j = 0; j < 2; ++j) {
      const int idx = t + j * 256;          // [0,512): (dd, f-quad) quad-fastest
      const int dd = idx >> 2, f4 = idx & 3;
      float4 v;
      v.x = lds[(4 * f4 + 0) * 129 + dd];
      v.y = lds[(4 * f4 + 1) * 129 + dd];
      v.z = lds[(4 * f4 + 2) * 129 + dd];
      v.w = lds[(4 * f4 + 3) * 129 + dd];
      dst4[dd * (FF / 4) + f4] = v;
    }
  } else if (blk < NF + NR) {
    // ---- r_proj for 16 robot rows, natural layout ----
    const int base = (blk - NF) * ROWS;
    const float4* src = (const float4*)(robot + (size_t)base * DD);
    #pragma unroll
    for (int i = 0; i < 2; ++i) ((float4*)lds)[t + 256 * i] = src[t + 256 * i];
    __syncthreads();
    const int d = t & 127, fh = t >> 7;
    float acc[8];
    #pragma unroll
    for (int i = 0; i < 8; ++i) acc[i] = 0.f;
    #pragma unroll 4
    for (int k = 0; k < DD; ++k) {
      const float w = W1[k * DD + d];  // W1r
      #pragma unroll
      for (int i = 0; i < 8; ++i)
        acc[i] = fmaf(lds[(fh * 8 + i) * 128 + k], w, acc[i]);
    }
    #pragma unroll
    for (int i = 0; i < 8; ++i)
      rproj[(size_t)(base + fh * 8 + i) * DD + d] = acc[i];  // coalesced over d
  } else if (t < DD) {
    // ---- wd[d] = colsum of W1d ----
    float acc = 0.f;
    #pragma unroll 4
    for (int k = 0; k < DD; ++k) acc += W1[(2 * DD + k) * DD + t];
    wd[t] = acc;
  }
}

__global__ __launch_bounds__(1024) void fused_kernel(
    const float* __restrict__ robot, const float* __restrict__ frontier,
    const float* __restrict__ geo,
    const float* __restrict__ b1, const float* __restrict__ W2,
    const float* __restrict__ b2, const float* __restrict__ Wn,
    const float* __restrict__ bn,
    const float* __restrict__ ws, float* __restrict__ out) {
  const int br = blockIdx.x;  // b*R + r
  const int b  = br >> 6;
  const int t  = threadIdx.x;

  const float* fpT   = ws;
  const float* rproj = ws + RPROJ_OFF;
  const float* wd    = ws + WD_OFF;

  __shared__ float rpb[DD], wds[DD], w2s[DD];
  __shared__ float wlds[FF];
  __shared__ float part[32][DD];   // message partials [f-group][d]
  __shared__ float red2[8][DD];    // 2nd-stage partials (reused for final matvec)
  __shared__ float combs[2 * DD];
  __shared__ float red[32];

  if (t < DD) {
    rpb[t] = rproj[br * DD + t] + b1[t];
    wds[t] = wd[t];
    w2s[t] = W2[t];
  }
  __syncthreads();

  // ---- scores: 1 f per thread ----
  const float g = geo[(size_t)br * FF + t];
  const float* fb = fpT + (size_t)b * DD * FF;
  float acc = 0.f;
  #pragma unroll 16
  for (int d = 0; d < DD; ++d) {
    const float h = fmaf(g, wds[d], rpb[d]) + fb[d * FF + t];  // coalesced 4KB/iter
    acc = fmaf(fmaxf(h, 0.f), w2s[d], acc);
  }
  const float s = fmaxf(acc + b2[0], 0.f);

  // ---- softmax over 1024 values, 16 waves ----
  float m = s;
  #pragma unroll
  for (int off = 32; off >= 1; off >>= 1) m = fmaxf(m, __shfl_xor(m, off, 64));
  if ((t & 63) == 0) red[t >> 6] = m;
  __syncthreads();
  float bm = red[0];
  #pragma unroll
  for (int i = 1; i < 16; ++i) bm = fmaxf(bm, red[i]);
  const float e = __expf(s - bm);
  float sum = e;
  #pragma unroll
  for (int off = 32; off >= 1; off >>= 1) sum += __shfl_xor(sum, off, 64);
  if ((t & 63) == 0) red[16 + (t >> 6)] = sum;
  __syncthreads();
  float bs = 0.f;
  #pragma unroll
  for (int i = 0; i < 16; ++i) bs += red[16 + i];
  const float w = e * (1.0f / bs);
  wlds[t] = w;
  float* ew = out + BB * RR * DD;  // edge_weights output
  ew[(size_t)br * FF + t] = w;
  __syncthreads();

  // ---- messages: msg[d] = sum_f w[f]*frontier[b][f][d]; float4 over d ----
  {
    const int c = t & 31, fg = t >> 5;  // 32 f-groups × 32 float4-columns
    const float4* fr4 = (const float4*)(frontier + (size_t)b * FF * DD);
    float ax = 0.f, ay = 0.f, az = 0.f, aw = 0.f;
    #pragma unroll 8
    for (int i = 0; i < 32; ++i) {
      const int f = fg * 32 + i;
      const float wf = wlds[f];           // broadcast
      const float4 v = fr4[f * 32 + c];   // 512B contiguous per 32 lanes
      ax = fmaf(wf, v.x, ax);
      ay = fmaf(wf, v.y, ay);
      az = fmaf(wf, v.z, az);
      aw = fmaf(wf, v.w, aw);
    }
    part[fg][4 * c]     = ax;
    part[fg][4 * c + 1] = ay;
    part[fg][4 * c + 2] = az;
    part[fg][4 * c + 3] = aw;
  }
  __syncthreads();
  {
    const int d = t & 127, gg = t >> 7;  // 8 groups of 4
    red2[gg][d] = part[gg * 4][d] + part[gg * 4 + 1][d] +
                  part[gg * 4 + 2][d] + part[gg * 4 + 3][d];
  }
  __syncthreads();
  if (t < DD) {
    float msg = 0.f;
    #pragma unroll
    for (int i = 0; i < 8; ++i) msg += red2[i][t];
    combs[DD + t] = msg;
  } else if (t < 2 * DD) {
    combs[t - DD] = robot[(size_t)br * DD + (t - DD)];
  }
  __syncthreads();

  // ---- new_robot[j] = relu(sum_k combs[k]*Wn[k][j] + bn[j]) ----
  {
    const int j = t & 127, kh = t >> 7;  // 8 k-groups of 32
    float fa = 0.f;
    #pragma unroll 8
    for (int i = 0; i < 32; ++i) {
      const int k = kh * 32 + i;
      fa = fmaf(combs[k], Wn[k * DD + j], fa);  // coalesced over j
    }
    red2[kh][j] = fa;  // safe: prior red2 reads completed at last barrier
  }
  __syncthreads();
  if (t < DD) {
    float v = bn[t];
    #pragma unroll
    for (int i = 0; i < 8; ++i) v += red2[i][t];
    out[(size_t)br * DD + t] = fmaxf(v, 0.f);
  }
}

extern "C" void kernel_launch(void* const* d_in, const int* in_sizes, int n_in,
                              void* d_out, int out_size, void* d_ws, size_t ws_size,
                              hipStream_t stream) {
  const float* robot    = (const float*)d_in[0];
  const float* frontier = (const float*)d_in[1];
  const float* geo      = (const float*)d_in[2];
  const float* W1       = (const float*)d_in[3];
  const float* b1       = (const float*)d_in[4];
  const float* W2       = (const float*)d_in[5];
  const float* b2       = (const float*)d_in[6];
  const float* Wn       = (const float*)d_in[7];
  const float* bn       = (const float*)d_in[8];
  float* out = (float*)d_out;
  float* ws  = (float*)d_ws;

  const int grid1 = (BB * FF) / ROWS + (BB * RR) / ROWS + 1;  // 273
  proj_kernel<<<grid1, 256, 0, stream>>>(robot, frontier, W1, ws);
  fused_kernel<<<BB * RR, 1024, 0, stream>>>(robot, frontier, geo, b1, W2, b2,
                                             Wn, bn, ws, out);
}